// Round 4
// baseline (9264.220 us; speedup 1.0000x reference)
//
#include <hip/hip_runtime.h>
#include <math.h>

#define NN 50000
#define EE 800000

__device__ __forceinline__ float silu_f(float x) {
    return x / (1.f + __expf(-x));
}

// ---------------- node embedding: h_s = embed_w[sp]/sqrt(5), h_v = 0 ----------------
__global__ void k_embed(const int* __restrict__ species, const float* __restrict__ embed_w,
                        float* __restrict__ h_s, float* __restrict__ h_v) {
    int n = blockIdx.x * 256 + threadIdx.x;
    if (n >= NN) return;
    int sp = species[n];
    const float rs5 = 0.4472135954999579f; // 1/sqrt(5)
#pragma unroll
    for (int u = 0; u < 32; ++u) h_s[n * 32 + u] = embed_w[sp * 32 + u] * rs5;
#pragma unroll
    for (int t = 0; t < 96; ++t) h_v[n * 96 + t] = 0.f;
}

// ---------------- weight transposes ----------------
__global__ void k_wtrans(const float* __restrict__ mlp_w0, const float* __restrict__ mlp_w2,
                         float* __restrict__ w0T, float* __restrict__ w2T) {
    int idx = blockIdx.x * 256 + threadIdx.x;
    if (idx < 1024) {
        int l = idx >> 9, rem = idx & 511, h = rem >> 3, k = rem & 7;
        w0T[idx] = mlp_w0[l * 512 + k * 64 + h];
    }
    if (idx < 16384) {
        int l = idx >> 13, rem = idx & 8191, m = rem >> 6, j = rem & 63;
        w2T[idx] = mlp_w2[l * 8192 + j * 128 + m];
    }
}

// ---------------- CSR build ----------------
__global__ void k_hist(const int* __restrict__ recv, int* __restrict__ deg) {
    int e = blockIdx.x * 256 + threadIdx.x;
    if (e < EE) atomicAdd(&deg[recv[e]], 1);
}

__global__ void k_scan(const int* __restrict__ deg, int* __restrict__ row_start,
                       int* __restrict__ cursor) {
    __shared__ int part[256];
    int t = threadIdx.x;
    int lo = t * 196, hi = lo + 196 > NN ? NN : lo + 196;
    int s = 0;
    for (int i = lo; i < hi; ++i) s += deg[i];
    part[t] = s;
    __syncthreads();
    int acc = 0;
    for (int i = 0; i < t; ++i) acc += part[i];
    int run = acc;
    for (int i = lo; i < hi; ++i) {
        row_start[i] = run;
        cursor[i] = run;
        run += deg[i];
    }
    if (t == 255) row_start[NN] = run;
}

__global__ void k_fill(const int* __restrict__ recv, int* __restrict__ cursor,
                       int* __restrict__ csr_edge) {
    int e = blockIdx.x * 256 + threadIdx.x;
    if (e >= EE) return;
    int p = atomicAdd(&cursor[recv[e]], 1);
    csr_edge[p] = e;
}

// ---------------- per-layer self-interaction linear: hs, hv ----------------
__global__ void k_node_prep(const float* __restrict__ h_s, const float* __restrict__ h_v,
                            const float* __restrict__ w_lin1_s, const float* __restrict__ w_lin1_v,
                            float* __restrict__ hs, float* __restrict__ hv) {
    int idx = blockIdx.x * 256 + threadIdx.x;
    if (idx >= 4 * NN) return;
    int c = idx / NN;
    int n = idx - c * NN;
    const float* in;
    const float* W;
    float* out;
    if (c == 0) { in = h_s + n * 32; W = w_lin1_s; out = hs + n * 32; }
    else        { in = h_v + n * 96 + (c - 1) * 32; W = w_lin1_v; out = hv + n * 96 + (c - 1) * 32; }
    float acc[32];
#pragma unroll
    for (int v = 0; v < 32; ++v) acc[v] = 0.f;
    for (int u = 0; u < 32; ++u) {
        float xu = in[u];
        const float* Wr = W + u * 32;
#pragma unroll
        for (int v = 0; v < 32; ++v) acc[v] += xu * Wr[v];
    }
    const float rs32 = 0.17677669529663687f; // 1/sqrt(32)
#pragma unroll
    for (int v = 0; v < 32; ++v) out[v] = acc[v] * rs32;
}

// ---------------- fused edge kernel: 8 lanes per edge ----------------
// block = 256 threads = 32 CSR positions. lane-in-group tt = tid&7, group g = tid>>3.
// Phase 1: lane computes a1 for j = tt*8..tt*8+7, partial a2[64]; shfl_xor(1,2,4)
//          reduce -> every lane holds the full a2[64] in registers.
// Phase 2: lane handles u = tt*4..tt*4+3; feature reads are float4, each 128B
//          line covered exactly once by its 8-lane group.
// Scatter: 16-row x 257-stride LDS window + global-atomic fallback; flush with
//          interior-ownership test (plain store) else atomicAdd.
#define WROWS 16
#define WSTRIDE 257
__global__ __launch_bounds__(256) void k_fused(
    const float* __restrict__ evec, const int* __restrict__ senders,
    const int* __restrict__ receivers, const int* __restrict__ csr_edge,
    const int* __restrict__ row_start,
    const float* __restrict__ hs, const float* __restrict__ hv,
    const float* __restrict__ w0T, const float* __restrict__ w1,
    const float* __restrict__ w2T,
    float* __restrict__ n0, float* __restrict__ n1) {
    __shared__ float acc[WROWS * WSTRIDE];
    __shared__ int sh_base, sh_last;
    int tid = threadIdx.x;
    int g = tid >> 3, tt = tid & 7;
    int p0 = blockIdx.x * 32;
    int pos = p0 + g;                  // EE == 25000*32, always valid

    for (int i = tid; i < WROWS * WSTRIDE; i += 256) acc[i] = 0.f;

    int e = csr_edge[pos];
    int rv = receivers[e];
    int s = senders[e];
    if (tid == 0)   sh_base = rv;
    if (tid == 255) sh_last = rv;
    __syncthreads();
    int node_base = sh_base;

    // ---- geometry (redundant across the 8 lanes of a group; cheap) ----
    float x = evec[e * 3 + 0], y = evec[e * 3 + 1], z = evec[e * 3 + 2];
    float r = sqrtf(x * x + y * y + z * z + 1e-12f);
    float ir = 1.f / r;
    const float s3 = 1.7320508075688772f;
    float shx = s3 * x * ir, shy = s3 * y * ir, shz = s3 * z * ir;
    float xx = r * 0.2f;
    float env = 0.f;
    if (xx < 1.f) {
        float x2 = xx * xx, x3 = x2 * xx, x6 = x3 * x3, x7 = x6 * xx, x8 = x7 * xx;
        env = 1.f - 28.f * x6 + 48.f * x7 - 21.f * x8;
    }
    float coef = 0.6324555320336759f * env * ir; // sqrt(2/5) * env / r
    const float w5 = 0.6283185307179586f;        // pi/5
    float eeR[8];
#pragma unroll
    for (int k = 0; k < 8; ++k) eeR[k] = coef * __sinf(w5 * (float)(k + 1) * r);

    // ---- prefetch this lane's feature slice (exactly-once, full-line float4) ----
    int u0 = tt * 4;
    float4 es4 = *(const float4*)(hs + s * 32 + u0);
    float4 evx = *(const float4*)(hv + s * 96 + u0);
    float4 evy = *(const float4*)(hv + s * 96 + 32 + u0);
    float4 evz = *(const float4*)(hv + s * 96 + 64 + u0);

    // ---- phase 1: MLP, j split across 8 lanes ----
    float a2[64];
#pragma unroll
    for (int h = 0; h < 64; ++h) a2[h] = 0.f;
    const float rs8 = 0.35355339059327373f; // 1/sqrt(8)
    int j0 = tt * 8;
#pragma unroll
    for (int jj = 0; jj < 8; ++jj) {
        const float* w0r = w0T + (j0 + jj) * 8;
        float p = 0.f;
#pragma unroll
        for (int k = 0; k < 8; ++k) p += eeR[k] * w0r[k];
        float a1j = silu_f(p * rs8);
        const float* w1r = w1 + (j0 + jj) * 64;
#pragma unroll
        for (int h = 0; h < 64; ++h) a2[h] += a1j * w1r[h];
    }
    // reduce partial a2 across the 8 lanes of the group; every lane gets the sum
#pragma unroll
    for (int h = 0; h < 64; ++h) {
        float v = a2[h];
        v += __shfl_xor(v, 1);
        v += __shfl_xor(v, 2);
        v += __shfl_xor(v, 4);
        a2[h] = silu_f(v * 0.125f);
    }

    // ---- phase 2: TP for u = u0..u0+3 ----
    int w = rv - node_base;
    bool inwin = (w < WROWS);
    float* arow = acc + w * WSTRIDE;
    const float rs3 = 0.5773502691896258f; // 1/sqrt(3)
    float* n0r = n0 + rv * 64;
    float* n1r = n1 + rv * 192;
    const float* esp = (const float*)&es4;
    const float* ev0p = (const float*)&evx;
    const float* ev1p = (const float*)&evy;
    const float* ev2p = (const float*)&evz;

#pragma unroll
    for (int uu = 0; uu < 4; ++uu) {
        int u = u0 + uu;
        const float* c1 = w2T + u * 64;
        const float* c2 = w2T + (32 + u) * 64;
        const float* c3 = w2T + (64 + u) * 64;
        const float* c4 = w2T + (96 + u) * 64;
        float d1 = 0.f, d2 = 0.f, d3 = 0.f, d4 = 0.f;
#pragma unroll
        for (int j = 0; j < 64; ++j) {
            float aj = a2[j];
            d1 += aj * c1[j];
            d2 += aj * c2[j];
            d3 += aj * c3[j];
            d4 += aj * c4[j];
        }
        float es = esp[uu];
        float ev0 = ev0p[uu], ev1 = ev1p[uu], ev2 = ev2p[uu];
        float dot = ev0 * shx + ev1 * shy + ev2 * shz;
        float o0a = d1 * es;
        float o0b = d2 * dot * rs3;
        float t3 = d3 * es;
        float v2 = t3 * shx, v3 = d4 * ev0;
        float v4 = t3 * shy, v5 = d4 * ev1;
        float v6 = t3 * shz, v7 = d4 * ev2;
        if (inwin) {
            atomicAdd(arow + u, o0a);
            atomicAdd(arow + 32 + u, o0b);
            atomicAdd(arow + 64 + u, v2);
            atomicAdd(arow + 96 + u, v3);
            atomicAdd(arow + 128 + u, v4);
            atomicAdd(arow + 160 + u, v5);
            atomicAdd(arow + 192 + u, v6);
            atomicAdd(arow + 224 + u, v7);
        } else { // rare window overflow
            atomicAdd(n0r + u, o0a);
            atomicAdd(n0r + 32 + u, o0b);
            atomicAdd(n1r + u, v2);
            atomicAdd(n1r + 32 + u, v3);
            atomicAdd(n1r + 64 + u, v4);
            atomicAdd(n1r + 96 + u, v5);
            atomicAdd(n1r + 128 + u, v6);
            atomicAdd(n1r + 160 + u, v7);
        }
    }
    __syncthreads();

    // flush window: plain store for block-owned nodes, atomicAdd for boundary
    int span = sh_last - node_base;
    if (span > WROWS - 1) span = WROWS - 1;
    for (int wl = 0; wl <= span; ++wl) {
        int n = node_base + wl;
        float v = acc[wl * WSTRIDE + tid];
        bool interior = (row_start[n] >= p0) && (row_start[n + 1] <= p0 + 32);
        float* dest = (tid < 64) ? (n0 + n * 64 + tid) : (n1 + n * 192 + (tid - 64));
        if (interior) *dest = v;
        else if (v != 0.f) atomicAdd(dest, v);
    }
}

// ---------------- node update: lin2 + residual + gated nonlinearity ----------------
__global__ void k_node_update(const int* __restrict__ species,
                              const float* __restrict__ n0, const float* __restrict__ n1,
                              const float* __restrict__ w_lin2_s, const float* __restrict__ w_lin2_v,
                              const float* __restrict__ w_res_s, const float* __restrict__ w_res_v,
                              float* __restrict__ h_s, float* __restrict__ h_v) {
    int n = blockIdx.x * 256 + threadIdx.x;
    if (n >= NN) return;
    int sp = species[n];
    const float sc_l2 = 1.f / 128.f;              // (1/16 neigh) * (1/sqrt(64) lin2)
    const float rs160 = 0.07905694150420949f;     // 1/sqrt(160)

    float sout[64];
#pragma unroll
    for (int k = 0; k < 64; ++k) sout[k] = 0.f;
    const float* n0r = n0 + n * 64;
    for (int j = 0; j < 64; ++j) {
        float xv = n0r[j] * sc_l2;
        const float* Wr = w_lin2_s + j * 64;
#pragma unroll
        for (int k = 0; k < 64; ++k) sout[k] += xv * Wr[k];
    }
    const float* hsr = h_s + n * 32;
    for (int u = 0; u < 32; ++u) {
        float xv = hsr[u] * rs160;
        const float* Wr = w_res_s + (u * 5 + sp) * 64;
#pragma unroll
        for (int k = 0; k < 64; ++k) sout[k] += xv * Wr[k];
    }
    float g[32], hsnew[32];
#pragma unroll
    for (int v = 0; v < 32; ++v) g[v] = silu_f(sout[32 + v]);
#pragma unroll
    for (int v = 0; v < 32; ++v) hsnew[v] = silu_f(sout[v]);

    for (int i = 0; i < 3; ++i) {
        float vacc[32];
#pragma unroll
        for (int v = 0; v < 32; ++v) vacc[v] = 0.f;
        const float* n1r = n1 + n * 192 + i * 64;
        for (int u = 0; u < 64; ++u) {
            float xv = n1r[u] * sc_l2;
            const float* Wr = w_lin2_v + u * 32;
#pragma unroll
            for (int v = 0; v < 32; ++v) vacc[v] += xv * Wr[v];
        }
        const float* hvr = h_v + n * 96 + i * 32;
        for (int u = 0; u < 32; ++u) {
            float xv = hvr[u] * rs160;
            const float* Wr = w_res_v + (u * 5 + sp) * 32;
#pragma unroll
            for (int v = 0; v < 32; ++v) vacc[v] += xv * Wr[v];
        }
        float* outp = h_v + n * 96 + i * 32;
#pragma unroll
        for (int v = 0; v < 32; ++v) outp[v] = vacc[v] * g[v];
    }
#pragma unroll
    for (int v = 0; v < 32; ++v) h_s[n * 32 + v] = hsnew[v];
}

// ---------------- readout ----------------
__global__ void k_readout(const float* __restrict__ h_s, const float* __restrict__ w_out1,
                          const float* __restrict__ w_out2, float* __restrict__ out) {
    int n = blockIdx.x * 256 + threadIdx.x;
    if (n >= NN) return;
    float zacc[16];
#pragma unroll
    for (int j = 0; j < 16; ++j) zacc[j] = 0.f;
    const float* hsr = h_s + n * 32;
    for (int u = 0; u < 32; ++u) {
        float xv = hsr[u];
        const float* Wr = w_out1 + u * 16;
#pragma unroll
        for (int j = 0; j < 16; ++j) zacc[j] += xv * Wr[j];
    }
    float ev = 0.f;
#pragma unroll
    for (int j = 0; j < 16; ++j) ev += zacc[j] * w_out2[j];
    out[n] = ev * 0.17677669529663687f * 0.25f; // 1/sqrt(32) * 1/sqrt(16)
}

extern "C" void kernel_launch(void* const* d_in, const int* in_sizes, int n_in,
                              void* d_out, int out_size, void* d_ws, size_t ws_size,
                              hipStream_t stream) {
    const float* evec     = (const float*)d_in[0];
    const int*   species  = (const int*)d_in[1];
    const int*   senders  = (const int*)d_in[2];
    const int*   receivers= (const int*)d_in[3];
    const float* embed_w  = (const float*)d_in[4];
    const float* w_res_s  = (const float*)d_in[5];
    const float* w_res_v  = (const float*)d_in[6];
    const float* w_lin1_s = (const float*)d_in[7];
    const float* w_lin1_v = (const float*)d_in[8];
    const float* mlp_w0   = (const float*)d_in[9];
    const float* mlp_w1   = (const float*)d_in[10];
    const float* mlp_w2   = (const float*)d_in[11];
    const float* w_lin2_s = (const float*)d_in[12];
    const float* w_lin2_v = (const float*)d_in[13];
    const float* w_out1   = (const float*)d_in[14];
    const float* w_out2   = (const float*)d_in[15];

    float* ws = (float*)d_ws;
    size_t off = 0;
    auto alloc = [&](size_t n) { float* p = ws + off; off += (n + 3) & ~(size_t)3; return p; };

    float* h_s = alloc(NN * 32);
    float* h_v = alloc(NN * 96);
    float* hs  = alloc(NN * 32);
    float* hv  = alloc(NN * 96);
    float* n0b = alloc(NN * 64);
    float* n1b = alloc(NN * 192);
    float* w0T = alloc(1024);
    float* w2T = alloc(16384);
    int*   deg = (int*)alloc(NN);
    int*   row_start = (int*)alloc(NN + 1);
    int*   cursor = (int*)alloc(NN);
    int*   csr_edge = (int*)alloc(EE);
    // total ~26.6M floats ~= 106 MB

    k_embed<<<(NN + 255) / 256, 256, 0, stream>>>(species, embed_w, h_s, h_v);
    k_wtrans<<<64, 256, 0, stream>>>(mlp_w0, mlp_w2, w0T, w2T);

    hipMemsetAsync(deg, 0, NN * 4, stream);
    k_hist<<<(EE + 255) / 256, 256, 0, stream>>>(receivers, deg);
    k_scan<<<1, 256, 0, stream>>>(deg, row_start, cursor);
    k_fill<<<(EE + 255) / 256, 256, 0, stream>>>(receivers, cursor, csr_edge);

    for (int l = 0; l < 2; ++l) {
        k_node_prep<<<(4 * NN + 255) / 256, 256, 0, stream>>>(
            h_s, h_v, w_lin1_s + l * 1024, w_lin1_v + l * 1024, hs, hv);
        hipMemsetAsync(n0b, 0, (size_t)NN * 64 * 4, stream);
        hipMemsetAsync(n1b, 0, (size_t)NN * 192 * 4, stream);
        k_fused<<<EE / 32, 256, 0, stream>>>(
            evec, senders, receivers, csr_edge, row_start, hs, hv,
            w0T + l * 512, mlp_w1 + l * 4096, w2T + l * 8192, n0b, n1b);
        k_node_update<<<(NN + 255) / 256, 256, 0, stream>>>(
            species, n0b, n1b,
            w_lin2_s + l * 4096, w_lin2_v + l * 2048,
            w_res_s + l * 10240, w_res_v + l * 5120, h_s, h_v);
    }
    k_readout<<<(NN + 255) / 256, 256, 0, stream>>>(h_s, w_out1, w_out2, (float*)d_out);
}

// Round 5
// 3602.464 us; speedup vs baseline: 2.5716x; 2.5716x over previous
//
#include <hip/hip_runtime.h>
#include <math.h>

#define NN 50000
#define EE 800000

__device__ __forceinline__ float silu_f(float x) {
    return x / (1.f + __expf(-x));
}

// ---------------- node embedding: h_s = embed_w[sp]/sqrt(5), h_v = 0 ----------------
__global__ void k_embed(const int* __restrict__ species, const float* __restrict__ embed_w,
                        float* __restrict__ h_s, float* __restrict__ h_v) {
    int n = blockIdx.x * 256 + threadIdx.x;
    if (n >= NN) return;
    int sp = species[n];
    const float rs5 = 0.4472135954999579f; // 1/sqrt(5)
#pragma unroll
    for (int u = 0; u < 32; ++u) h_s[n * 32 + u] = embed_w[sp * 32 + u] * rs5;
#pragma unroll
    for (int t = 0; t < 96; ++t) h_v[n * 96 + t] = 0.f;
}

// ---------------- weight transposes ----------------
__global__ void k_wtrans(const float* __restrict__ mlp_w0, const float* __restrict__ mlp_w2,
                         float* __restrict__ w0T, float* __restrict__ w2T) {
    int idx = blockIdx.x * 256 + threadIdx.x;
    if (idx < 1024) {
        int l = idx >> 9, rem = idx & 511, h = rem >> 3, k = rem & 7;
        w0T[idx] = mlp_w0[l * 512 + k * 64 + h];
    }
    if (idx < 16384) {
        int l = idx >> 13, rem = idx & 8191, m = rem >> 6, j = rem & 63;
        w2T[idx] = mlp_w2[l * 8192 + j * 128 + m];
    }
}

// ---------------- CSR build ----------------
__global__ void k_hist(const int* __restrict__ recv, int* __restrict__ deg) {
    int e = blockIdx.x * 256 + threadIdx.x;
    if (e < EE) atomicAdd(&deg[recv[e]], 1);
}

__global__ void k_scan(const int* __restrict__ deg, int* __restrict__ row_start,
                       int* __restrict__ cursor) {
    __shared__ int part[256];
    int t = threadIdx.x;
    int lo = t * 196, hi = lo + 196 > NN ? NN : lo + 196;
    int s = 0;
    for (int i = lo; i < hi; ++i) s += deg[i];
    part[t] = s;
    __syncthreads();
    int acc = 0;
    for (int i = 0; i < t; ++i) acc += part[i];
    int run = acc;
    for (int i = lo; i < hi; ++i) {
        row_start[i] = run;
        cursor[i] = run;
        run += deg[i];
    }
    if (t == 255) row_start[NN] = run;
}

__global__ void k_fill(const int* __restrict__ recv, int* __restrict__ cursor,
                       int* __restrict__ csr_edge) {
    int e = blockIdx.x * 256 + threadIdx.x;
    if (e >= EE) return;
    int p = atomicAdd(&cursor[recv[e]], 1);
    csr_edge[p] = e;
}

// ---------------- one-time gather into CSR order ----------------
__global__ void k_gather(const int* __restrict__ csr_edge, const int* __restrict__ senders,
                         const int* __restrict__ receivers, const float* __restrict__ evec,
                         int* __restrict__ csr_send, int* __restrict__ csr_recv,
                         float* __restrict__ ev3) {
    int p = blockIdx.x * 256 + threadIdx.x;
    if (p >= EE) return;
    int e = csr_edge[p];
    csr_send[p] = senders[e];
    csr_recv[p] = receivers[e];
    ev3[p * 3 + 0] = evec[e * 3 + 0];
    ev3[p * 3 + 1] = evec[e * 3 + 1];
    ev3[p * 3 + 2] = evec[e * 3 + 2];
}

// ---------------- per-layer self-interaction linear -> interleaved feat ----------------
// feat[n][c][0..3]=hs[4c..4c+3], [4..7]=hv_x, [8..11]=hv_y, [12..15]=hv_z  (c=0..7)
__global__ void k_node_prep2(const float* __restrict__ h_s, const float* __restrict__ h_v,
                             const float* __restrict__ w_lin1_s, const float* __restrict__ w_lin1_v,
                             float* __restrict__ feat) {
    int n = blockIdx.x * 256 + threadIdx.x;
    if (n >= NN) return;
    const float rs32 = 0.17677669529663687f; // 1/sqrt(32)
    float* fb = feat + (size_t)n * 128;
    { // half 1: scalars S and vector-x X
        float S[32], X[32];
#pragma unroll
        for (int v = 0; v < 32; ++v) { S[v] = 0.f; X[v] = 0.f; }
        for (int u = 0; u < 32; ++u) {
            float xs = h_s[n * 32 + u];
            float xx = h_v[n * 96 + u];
            const float* Ws = w_lin1_s + u * 32;
            const float* Wv = w_lin1_v + u * 32;
#pragma unroll
            for (int v = 0; v < 32; ++v) { S[v] += xs * Ws[v]; X[v] += xx * Wv[v]; }
        }
#pragma unroll
        for (int c = 0; c < 8; ++c)
#pragma unroll
            for (int q = 0; q < 4; ++q) {
                fb[c * 16 + q]     = S[c * 4 + q] * rs32;
                fb[c * 16 + 4 + q] = X[c * 4 + q] * rs32;
            }
    }
    { // half 2: vector-y Y and vector-z Z
        float Y[32], Z[32];
#pragma unroll
        for (int v = 0; v < 32; ++v) { Y[v] = 0.f; Z[v] = 0.f; }
        for (int u = 0; u < 32; ++u) {
            float xy = h_v[n * 96 + 32 + u];
            float xz = h_v[n * 96 + 64 + u];
            const float* Wv = w_lin1_v + u * 32;
#pragma unroll
            for (int v = 0; v < 32; ++v) { Y[v] += xy * Wv[v]; Z[v] += xz * Wv[v]; }
        }
#pragma unroll
        for (int c = 0; c < 8; ++c)
#pragma unroll
            for (int q = 0; q < 4; ++q) {
                fb[c * 16 + 8 + q]  = Y[c * 4 + q] * rs32;
                fb[c * 16 + 12 + q] = Z[c * 4 + q] * rs32;
            }
    }
}

// ---------------- fused edge kernel: 1 thread/edge, wave-uniform weights ----------------
#define WROWS 32
#define WSTRIDE 257
__global__ __launch_bounds__(256) void k_fused2(
    const int* __restrict__ csr_send, const int* __restrict__ csr_recv,
    const float* __restrict__ ev3, const int* __restrict__ row_start,
    const float* __restrict__ feat,
    const float* __restrict__ w0T, const float* __restrict__ w1,
    const float* __restrict__ w2T,
    float* __restrict__ n0, float* __restrict__ n1) {
    __shared__ float acc[WROWS * WSTRIDE];
    __shared__ int sh_base, sh_last;
    int tid = threadIdx.x;
    int p0 = blockIdx.x * 256;
    int pos = p0 + tid;                 // EE == 3125*256, always valid

    for (int i = tid; i < WROWS * WSTRIDE; i += 256) acc[i] = 0.f;

    int s = csr_send[pos];
    int rv = csr_recv[pos];
    if (tid == 0)   sh_base = rv;
    if (tid == 255) sh_last = rv;
    __syncthreads();
    int node_base = sh_base;

    // ---- geometry ----
    float x = ev3[pos * 3 + 0], y = ev3[pos * 3 + 1], z = ev3[pos * 3 + 2];
    float r = sqrtf(x * x + y * y + z * z + 1e-12f);
    float ir = 1.f / r;
    const float s3 = 1.7320508075688772f;
    float shx = s3 * x * ir, shy = s3 * y * ir, shz = s3 * z * ir;
    float xx = r * 0.2f;
    float env = 0.f;
    if (xx < 1.f) {
        float x2 = xx * xx, x3 = x2 * xx, x6 = x3 * x3, x7 = x6 * xx, x8 = x7 * xx;
        env = 1.f - 28.f * x6 + 48.f * x7 - 21.f * x8;
    }
    float coef = 0.6324555320336759f * env * ir; // sqrt(2/5) * env / r
    const float w5 = 0.6283185307179586f;        // pi/5
    float eeR[8];
#pragma unroll
    for (int k = 0; k < 8; ++k) eeR[k] = coef * __sinf(w5 * (float)(k + 1) * r);

    // ---- radial MLP (wave-uniform weight rows -> s_load broadcast) ----
    float a2[64];
#pragma unroll
    for (int h = 0; h < 64; ++h) a2[h] = 0.f;
    const float rs8 = 0.35355339059327373f; // 1/sqrt(8)
    for (int j = 0; j < 64; ++j) {
        const float* w0r = w0T + j * 8;
        float p = 0.f;
#pragma unroll
        for (int k = 0; k < 8; ++k) p += eeR[k] * w0r[k];
        float a1j = silu_f(p * rs8);
        const float* w1r = w1 + j * 64;
#pragma unroll
        for (int h = 0; h < 64; ++h) a2[h] += a1j * w1r[h];
    }
#pragma unroll
    for (int h = 0; h < 64; ++h) a2[h] = silu_f(a2[h] * 0.125f);

    // ---- TP + scatter, u in chunks of 4; features: one 64B block per chunk ----
    int w = rv - node_base;
    bool inwin = (w < WROWS);
    float* arow = acc + w * WSTRIDE;
    const float rs3 = 0.5773502691896258f; // 1/sqrt(3)
    float* n0r = n0 + rv * 64;
    float* n1r = n1 + rv * 192;
    const float* fb = feat + (size_t)s * 128;

    for (int c = 0; c < 8; ++c) {
        float4 fS = *(const float4*)(fb + c * 16);
        float4 fX = *(const float4*)(fb + c * 16 + 4);
        float4 fY = *(const float4*)(fb + c * 16 + 8);
        float4 fZ = *(const float4*)(fb + c * 16 + 12);
        const float* esp = (const float*)&fS;
        const float* evx = (const float*)&fX;
        const float* evy = (const float*)&fY;
        const float* evz = (const float*)&fZ;
#pragma unroll
        for (int uu = 0; uu < 4; ++uu) {
            int u = c * 4 + uu;
            const float* c1 = w2T + u * 64;
            const float* c2 = w2T + (32 + u) * 64;
            const float* c3 = w2T + (64 + u) * 64;
            const float* c4 = w2T + (96 + u) * 64;
            float d1 = 0.f, d2 = 0.f, d3 = 0.f, d4 = 0.f;
#pragma unroll
            for (int j = 0; j < 64; ++j) {
                float aj = a2[j];
                d1 += aj * c1[j];
                d2 += aj * c2[j];
                d3 += aj * c3[j];
                d4 += aj * c4[j];
            }
            float es = esp[uu];
            float ev0 = evx[uu], ev1 = evy[uu], ev2 = evz[uu];
            float dot = ev0 * shx + ev1 * shy + ev2 * shz;
            float o0a = d1 * es;
            float o0b = d2 * dot * rs3;
            float t3 = d3 * es;
            float v2 = t3 * shx, v3 = d4 * ev0;
            float v4 = t3 * shy, v5 = d4 * ev1;
            float v6 = t3 * shz, v7 = d4 * ev2;
            if (inwin) {
                atomicAdd(arow + u, o0a);
                atomicAdd(arow + 32 + u, o0b);
                atomicAdd(arow + 64 + u, v2);
                atomicAdd(arow + 96 + u, v3);
                atomicAdd(arow + 128 + u, v4);
                atomicAdd(arow + 160 + u, v5);
                atomicAdd(arow + 192 + u, v6);
                atomicAdd(arow + 224 + u, v7);
            } else { // rare window overflow
                atomicAdd(n0r + u, o0a);
                atomicAdd(n0r + 32 + u, o0b);
                atomicAdd(n1r + u, v2);
                atomicAdd(n1r + 32 + u, v3);
                atomicAdd(n1r + 64 + u, v4);
                atomicAdd(n1r + 96 + u, v5);
                atomicAdd(n1r + 128 + u, v6);
                atomicAdd(n1r + 160 + u, v7);
            }
        }
    }
    __syncthreads();

    // flush window: plain store for block-owned nodes, atomicAdd for boundary
    int span = sh_last - node_base;
    if (span > WROWS - 1) span = WROWS - 1;
    for (int wl = 0; wl <= span; ++wl) {
        int n = node_base + wl;
        float v = acc[wl * WSTRIDE + tid];
        bool interior = (row_start[n] >= p0) && (row_start[n + 1] <= p0 + 256);
        float* dest = (tid < 64) ? (n0 + n * 64 + tid) : (n1 + n * 192 + (tid - 64));
        if (interior) *dest = v;
        else if (v != 0.f) atomicAdd(dest, v);
    }
}

// ---------------- node update: lin2 + residual + gated nonlinearity ----------------
__global__ void k_node_update(const int* __restrict__ species,
                              const float* __restrict__ n0, const float* __restrict__ n1,
                              const float* __restrict__ w_lin2_s, const float* __restrict__ w_lin2_v,
                              const float* __restrict__ w_res_s, const float* __restrict__ w_res_v,
                              float* __restrict__ h_s, float* __restrict__ h_v) {
    int n = blockIdx.x * 256 + threadIdx.x;
    if (n >= NN) return;
    int sp = species[n];
    const float sc_l2 = 1.f / 128.f;              // (1/16 neigh) * (1/sqrt(64) lin2)
    const float rs160 = 0.07905694150420949f;     // 1/sqrt(160)

    float sout[64];
#pragma unroll
    for (int k = 0; k < 64; ++k) sout[k] = 0.f;
    const float* n0r = n0 + n * 64;
    for (int j = 0; j < 64; ++j) {
        float xv = n0r[j] * sc_l2;
        const float* Wr = w_lin2_s + j * 64;
#pragma unroll
        for (int k = 0; k < 64; ++k) sout[k] += xv * Wr[k];
    }
    const float* hsr = h_s + n * 32;
    for (int u = 0; u < 32; ++u) {
        float xv = hsr[u] * rs160;
        const float* Wr = w_res_s + (u * 5 + sp) * 64;
#pragma unroll
        for (int k = 0; k < 64; ++k) sout[k] += xv * Wr[k];
    }
    float g[32], hsnew[32];
#pragma unroll
    for (int v = 0; v < 32; ++v) g[v] = silu_f(sout[32 + v]);
#pragma unroll
    for (int v = 0; v < 32; ++v) hsnew[v] = silu_f(sout[v]);

    for (int i = 0; i < 3; ++i) {
        float vacc[32];
#pragma unroll
        for (int v = 0; v < 32; ++v) vacc[v] = 0.f;
        const float* n1r = n1 + n * 192 + i * 64;
        for (int u = 0; u < 64; ++u) {
            float xv = n1r[u] * sc_l2;
            const float* Wr = w_lin2_v + u * 32;
#pragma unroll
            for (int v = 0; v < 32; ++v) vacc[v] += xv * Wr[v];
        }
        const float* hvr = h_v + n * 96 + i * 32;
        for (int u = 0; u < 32; ++u) {
            float xv = hvr[u] * rs160;
            const float* Wr = w_res_v + (u * 5 + sp) * 32;
#pragma unroll
            for (int v = 0; v < 32; ++v) vacc[v] += xv * Wr[v];
        }
        float* outp = h_v + n * 96 + i * 32;
#pragma unroll
        for (int v = 0; v < 32; ++v) outp[v] = vacc[v] * g[v];
    }
#pragma unroll
    for (int v = 0; v < 32; ++v) h_s[n * 32 + v] = hsnew[v];
}

// ---------------- readout ----------------
__global__ void k_readout(const float* __restrict__ h_s, const float* __restrict__ w_out1,
                          const float* __restrict__ w_out2, float* __restrict__ out) {
    int n = blockIdx.x * 256 + threadIdx.x;
    if (n >= NN) return;
    float zacc[16];
#pragma unroll
    for (int j = 0; j < 16; ++j) zacc[j] = 0.f;
    const float* hsr = h_s + n * 32;
    for (int u = 0; u < 32; ++u) {
        float xv = hsr[u];
        const float* Wr = w_out1 + u * 16;
#pragma unroll
        for (int j = 0; j < 16; ++j) zacc[j] += xv * Wr[j];
    }
    float ev = 0.f;
#pragma unroll
    for (int j = 0; j < 16; ++j) ev += zacc[j] * w_out2[j];
    out[n] = ev * 0.17677669529663687f * 0.25f; // 1/sqrt(32) * 1/sqrt(16)
}

extern "C" void kernel_launch(void* const* d_in, const int* in_sizes, int n_in,
                              void* d_out, int out_size, void* d_ws, size_t ws_size,
                              hipStream_t stream) {
    const float* evec     = (const float*)d_in[0];
    const int*   species  = (const int*)d_in[1];
    const int*   senders  = (const int*)d_in[2];
    const int*   receivers= (const int*)d_in[3];
    const float* embed_w  = (const float*)d_in[4];
    const float* w_res_s  = (const float*)d_in[5];
    const float* w_res_v  = (const float*)d_in[6];
    const float* w_lin1_s = (const float*)d_in[7];
    const float* w_lin1_v = (const float*)d_in[8];
    const float* mlp_w0   = (const float*)d_in[9];
    const float* mlp_w1   = (const float*)d_in[10];
    const float* mlp_w2   = (const float*)d_in[11];
    const float* w_lin2_s = (const float*)d_in[12];
    const float* w_lin2_v = (const float*)d_in[13];
    const float* w_out1   = (const float*)d_in[14];
    const float* w_out2   = (const float*)d_in[15];

    float* ws = (float*)d_ws;
    size_t off = 0;
    auto alloc = [&](size_t n) { float* p = ws + off; off += (n + 3) & ~(size_t)3; return p; };

    float* h_s  = alloc(NN * 32);
    float* h_v  = alloc(NN * 96);
    float* feat = alloc((size_t)NN * 128);
    float* n0b  = alloc(NN * 64);
    float* n1b  = alloc(NN * 192);
    float* w0T  = alloc(1024);
    float* w2T  = alloc(16384);
    int*   deg       = (int*)alloc(NN);
    int*   row_start = (int*)alloc(NN + 1);
    int*   cursor    = (int*)alloc(NN);
    int*   csr_edge  = (int*)alloc(EE);
    int*   csr_send  = (int*)alloc(EE);
    int*   csr_recv  = (int*)alloc(EE);
    float* ev3       = alloc((size_t)EE * 3);
    // total ~30.6M floats ~= 122 MB

    k_embed<<<(NN + 255) / 256, 256, 0, stream>>>(species, embed_w, h_s, h_v);
    k_wtrans<<<64, 256, 0, stream>>>(mlp_w0, mlp_w2, w0T, w2T);

    hipMemsetAsync(deg, 0, NN * 4, stream);
    k_hist<<<(EE + 255) / 256, 256, 0, stream>>>(receivers, deg);
    k_scan<<<1, 256, 0, stream>>>(deg, row_start, cursor);
    k_fill<<<(EE + 255) / 256, 256, 0, stream>>>(receivers, cursor, csr_edge);
    k_gather<<<(EE + 255) / 256, 256, 0, stream>>>(csr_edge, senders, receivers, evec,
                                                   csr_send, csr_recv, ev3);

    for (int l = 0; l < 2; ++l) {
        k_node_prep2<<<(NN + 255) / 256, 256, 0, stream>>>(
            h_s, h_v, w_lin1_s + l * 1024, w_lin1_v + l * 1024, feat);
        hipMemsetAsync(n0b, 0, (size_t)NN * 64 * 4, stream);
        hipMemsetAsync(n1b, 0, (size_t)NN * 192 * 4, stream);
        k_fused2<<<EE / 256, 256, 0, stream>>>(
            csr_send, csr_recv, ev3, row_start, feat,
            w0T + l * 512, mlp_w1 + l * 4096, w2T + l * 8192, n0b, n1b);
        k_node_update<<<(NN + 255) / 256, 256, 0, stream>>>(
            species, n0b, n1b,
            w_lin2_s + l * 4096, w_lin2_v + l * 2048,
            w_res_s + l * 10240, w_res_v + l * 5120, h_s, h_v);
    }
    k_readout<<<(NN + 255) / 256, 256, 0, stream>>>(h_s, w_out1, w_out2, (float*)d_out);
}